// Round 13
// baseline (358.429 us; speedup 1.0000x reference)
//
#include <hip/hip_runtime.h>
#include <hip/hip_bf16.h>
#include <math.h>

#define B_  2
#define T_  2048
#define C_  1024
#define H_  16
#define D_  64
#define BT_ (B_*T_)

typedef __hip_bfloat16 bf16;
typedef short bf16x8 __attribute__((ext_vector_type(8)));
typedef float floatx4 __attribute__((ext_vector_type(4)));

struct alignas(8) bf4 { bf16 v[4]; };

#define GLOAD_LDS16(g, l) __builtin_amdgcn_global_load_lds(            \
    (const __attribute__((address_space(1))) void*)(g),                \
    (__attribute__((address_space(3))) void*)(l), 16, 0, 0)

// ---------------------------------------------------------------- LayerNorm body
__device__ __forceinline__ void ln_body(const float* __restrict__ x,
    const float* __restrict__ w, const float* __restrict__ b,
    bf16* __restrict__ out, const int row)
{
    __shared__ float ps[4], ps2[4];
    __shared__ float sm, srs;
    const int tid = threadIdx.x;
    float4 v = ((const float4*)(x + (size_t)row * C_))[tid];
    float s  = v.x + v.y + v.z + v.w;
    float s2 = v.x*v.x + v.y*v.y + v.z*v.z + v.w*v.w;
    for (int off = 32; off > 0; off >>= 1) {
        s  += __shfl_down(s,  off);
        s2 += __shfl_down(s2, off);
    }
    const int wid = tid >> 6;
    if ((tid & 63) == 0) { ps[wid] = s; ps2[wid] = s2; }
    __syncthreads();
    if (tid == 0) {
        float ts  = ps[0] + ps[1] + ps[2] + ps[3];
        float ts2 = ps2[0] + ps2[1] + ps2[2] + ps2[3];
        float mean = ts * (1.0f / C_);
        float var  = ts2 * (1.0f / C_) - mean * mean;
        sm  = mean;
        srs = rsqrtf(var + 1e-5f);
    }
    __syncthreads();
    const float mean = sm, rs = srs;
    float4 wv = ((const float4*)w)[tid];
    float4 bv = ((const float4*)b)[tid];
    bf4 o;
    o.v[0] = __float2bfloat16((v.x - mean) * rs * wv.x + bv.x);
    o.v[1] = __float2bfloat16((v.y - mean) * rs * wv.y + bv.y);
    o.v[2] = __float2bfloat16((v.z - mean) * rs * wv.z + bv.z);
    o.v[3] = __float2bfloat16((v.w - mean) * rs * wv.w + bv.w);
    *(bf4*)(out + (size_t)row * C_ + tid * 4) = o;
}

__global__ __launch_bounds__(256) void ln_bf16_kernel(const float* __restrict__ x,
    const float* __restrict__ w, const float* __restrict__ b,
    bf16* __restrict__ out)
{
    ln_body(x, w, b, out, blockIdx.x);
}

// ------------------------------------------- weight fp32 [K][N] -> bf16 [N][K]
__device__ __forceinline__ void wconv_body(const float* __restrict__ W,
    bf16* __restrict__ Wt, int K, int N, int k0, int n0)
{
    __shared__ float L[64][65];
    const int t = threadIdx.x;
    const int r = t >> 4, c4 = t & 15;
    #pragma unroll
    for (int p = 0; p < 4; ++p) {
        const int kr = p * 16 + r;
        const float4 v = *(const float4*)(W + (size_t)(k0 + kr) * N + n0 + c4 * 4);
        L[kr][c4*4+0] = v.x; L[kr][c4*4+1] = v.y;
        L[kr][c4*4+2] = v.z; L[kr][c4*4+3] = v.w;
    }
    __syncthreads();
    #pragma unroll
    for (int p = 0; p < 4; ++p) {
        const int nr = p * 16 + r;
        bf4 o;
        o.v[0] = __float2bfloat16(L[c4*4+0][nr]);
        o.v[1] = __float2bfloat16(L[c4*4+1][nr]);
        o.v[2] = __float2bfloat16(L[c4*4+2][nr]);
        o.v[3] = __float2bfloat16(L[c4*4+3][nr]);
        *(bf4*)(Wt + (size_t)(n0 + nr) * K + k0 + c4 * 4) = o;
    }
}

// ---------------------------------------------------------- fused prologue
// flat grid, range-decoded:
//   [0,1024):    wconv4 (wq/wk/wv/wo -> wqkvT/woT), 16x16x4
//   [1024,3072): wconv2 (w1 -> w1T, w2 -> w2T), 16x64x2
//   [3072,7168): ln1 (x -> h), 4096 rows
//   [7168,7180): bias concat bq|bk|bv -> bqkv
__global__ __launch_bounds__(256) void prep_kernel(
    const float* __restrict__ x, const float* __restrict__ ln1_w,
    const float* __restrict__ ln1_b,
    const float* __restrict__ wq, const float* __restrict__ wk,
    const float* __restrict__ wv, const float* __restrict__ wo,
    const float* __restrict__ bq, const float* __restrict__ bk,
    const float* __restrict__ bv,
    const float* __restrict__ w1, const float* __restrict__ w2,
    bf16* __restrict__ h, bf16* __restrict__ wqkvT, bf16* __restrict__ woT,
    bf16* __restrict__ w1T, bf16* __restrict__ w2T,
    float* __restrict__ bqkv)
{
    const int b = blockIdx.x;
    if (b < 1024) {
        const int z = b >> 8, rem = b & 255;
        const float* W = (z == 0) ? wq : (z == 1) ? wk : (z == 2) ? wv : wo;
        bf16* Wt = (z == 3) ? woT : wqkvT + (size_t)z * 1024 * 1024;
        wconv_body(W, Wt, 1024, 1024, (rem & 15) * 64, (rem >> 4) * 64);
    } else if (b < 3072) {
        const int c = b - 1024, z = c >> 10, r = c & 1023;
        if (z == 0) wconv_body(w1, w1T, 1024, 4096, (r & 15) * 64, (r >> 4) * 64);
        else        wconv_body(w2, w2T, 4096, 1024, (r >> 4) * 64, (r & 15) * 64);
    } else if (b < 7168) {
        ln_body(x, ln1_w, ln1_b, h, b - 3072);
    } else {
        const int i = (b - 7168) * 256 + threadIdx.x;
        float v = (i < 1024) ? bq[i] : (i < 2048 ? bk[i - 1024] : bv[i - 2048]);
        bqkv[i] = v;
    }
}

// ----------------------------------------------------- split-K reduce (mlp2)
// out += p1 (z=0 slice already contains a + bias + res)
__global__ __launch_bounds__(256) void splitk2_kernel(
    float* __restrict__ out, const float* __restrict__ p1)
{
    const size_t i = (size_t)blockIdx.x * 256 + threadIdx.x;   // float4 idx
    float4 o = ((const float4*)out)[i];
    const float4 p = ((const float4*)p1)[i];
    o.x += p.x; o.y += p.y; o.z += p.z; o.w += p.w;
    ((float4*)out)[i] = o;
}

// -------------------------------------------------------------- MFMA GEMM (old 2-barrier 128-tile)
// kept for proj (mode 2) and mlp2 split-K (mode 4)
template<int TM, int TN, int BK>
__global__ __launch_bounds__(256) void mfma_gemm_t(
    const bf16* __restrict__ A, const bf16* __restrict__ Wt,
    const float* __restrict__ bias, const float* __restrict__ res,
    void* __restrict__ outv, bf16* __restrict__ vT, float* __restrict__ psplit,
    int M, int N, int K, int ldk, int mode)
{
    constexpr int MI = TM / 32;
    constexpr int NJ = TN / 32;
    constexpr int CPR = BK / 8;                       // 16B chunks per row
    constexpr int NSLOT = (TM + TN) * CPR / 256;
    __shared__ __align__(16) bf16 smem[(TM + TN) * BK];
    bf16* As = smem;
    bf16* Bs = smem + TM * BK;
    const int tid = threadIdx.x;
    const int w = tid >> 6, l = tid & 63;
    const int fm = l & 15, qd = l >> 4;
    const int m0 = blockIdx.x * TM, n0 = blockIdx.y * TN;
    const int bz = blockIdx.z;
    const int wr = (w >> 1) * (TM / 2), wc = (w & 1) * (TN / 2);

    const bf16* Ab = A  + (size_t)bz * K;
    const bf16* Wb = Wt + (size_t)bz * K;

    const bf16* gsrc[NSLOT];
    bf16* ldst[NSLOT];
    #pragma unroll
    for (int p = 0; p < NSLOT; ++p) {
        const int s = tid + p * 256;
        if (s < TM * CPR) {
            const int row = s / CPR, pos = s % CPR;
            const int ch = pos ^ (row & (CPR - 1));
            gsrc[p] = Ab + (size_t)(m0 + row) * ldk + ch * 8;
            ldst[p] = As + s * 8;
        } else {
            const int s2 = s - TM * CPR;
            const int row = s2 / CPR, pos = s2 % CPR;
            const int ch = pos ^ (row & (CPR - 1));
            gsrc[p] = Wb + (size_t)(n0 + row) * ldk + ch * 8;
            ldst[p] = Bs + s2 * 8;
        }
    }

    floatx4 acc[MI][NJ] = {};

    const int nk = K / BK;
    for (int kk = 0; kk < nk; ++kk) {
        const size_t ko = (size_t)kk * BK;
        __syncthreads();
        #pragma unroll
        for (int p = 0; p < NSLOT; ++p)
            GLOAD_LDS16(gsrc[p] + ko, ldst[p]);
        __syncthreads();
        #pragma unroll
        for (int ks = 0; ks < BK / 32; ++ks) {
            bf16x8 af[MI], bfr[NJ];
            #pragma unroll
            for (int i = 0; i < MI; ++i) {
                const int row = wr + i * 16 + fm;
                af[i] = *(const bf16x8*)(As + row * BK
                        + (((ks * 4 + qd) ^ (row & (CPR - 1))) * 8));
            }
            #pragma unroll
            for (int j = 0; j < NJ; ++j) {
                const int row = wc + j * 16 + fm;
                bfr[j] = *(const bf16x8*)(Bs + row * BK
                        + (((ks * 4 + qd) ^ (row & (CPR - 1))) * 8));
            }
            #pragma unroll
            for (int i = 0; i < MI; ++i)
                #pragma unroll
                for (int j = 0; j < NJ; ++j)
                    acc[i][j] = __builtin_amdgcn_mfma_f32_16x16x32_bf16(
                        af[i], bfr[j], acc[i][j], 0, 0, 0);
        }
    }

    const int col0 = n0 + wc;
    const int row0 = m0 + wr;
    const bool isv = (mode == 3) && (col0 >= 2048);
    const bool bounce = (mode == 0) || (mode == 1) || (mode == 3 && !isv);
    __syncthreads();

    if (bounce) {
        constexpr int RM = TM / 2, RN = TN / 2, CHN = RN / 8;
        bf16* eb = smem + w * (RM * RN);
        #pragma unroll
        for (int j = 0; j < NJ; ++j) {
            const int col = col0 + j * 16 + fm;
            const float bb = bias[col];
            const bool isq = (mode == 3) && (col0 + j * 16 < 1024);
            const int lc = j * 16 + fm;
            #pragma unroll
            for (int i = 0; i < MI; ++i) {
                floatx4 a = acc[i][j];
                #pragma unroll
                for (int r = 0; r < 4; ++r) {
                    float vv = a[r] + bb;
                    if (mode == 1) {
                        float zz = vv * (0.7978845608f + 0.0356774081f * vv * vv);
                        zz = fminf(zz, 15.0f);
                        const float e = __expf(2.0f * zz);
                        vv = vv * (e / (e + 1.0f));
                    }
                    if (isq) vv *= 0.125f;
                    const int lr = i * 16 + qd * 4 + r;
                    const int pch = ((lc >> 3) + 2 * qd) & (CHN - 1);
                    eb[lr * RN + pch * 8 + (lc & 7)] = __float2bfloat16(vv);
                }
            }
        }
        bf16* o = (bf16*)outv;
        #pragma unroll
        for (int c = 0; c < RM * RN / 512; ++c) {
            const int idx = c * 64 + l;
            const int row = idx / CHN;
            const int c8  = idx % CHN;
            const int pch = (c8 + 2 * ((row >> 2) & 3)) & (CHN - 1);
            const bf16x8 vv = *(const bf16x8*)(eb + row * RN + pch * 8);
            *(bf16x8*)(o + (size_t)(row0 + row) * N + col0 + c8 * 8) = vv;
        }
    } else {
        #pragma unroll
        for (int j = 0; j < NJ; ++j) {
            const int col = col0 + j * 16 + fm;
            const float bb = bias[col];
            #pragma unroll
            for (int i = 0; i < MI; ++i) {
                const int row = row0 + i * 16 + qd * 4;
                floatx4 a = acc[i][j];
                if (mode == 4) {
                    // split-K: z=0 -> out with bias+res folded; z=1 -> raw p1
                    if (bz == 0) {
                        float* o = (float*)outv;
                        #pragma unroll
                        for (int r = 0; r < 4; ++r)
                            o[(size_t)(row + r) * N + col] =
                                a[r] + bb + res[(size_t)(row + r) * N + col];
                    } else {
                        #pragma unroll
                        for (int r = 0; r < 4; ++r)
                            psplit[(size_t)(row + r) * N + col] = a[r];
                    }
                } else if (mode == 2) {
                    float* o = (float*)outv;
                    #pragma unroll
                    for (int r = 0; r < 4; ++r)
                        o[(size_t)(row + r) * N + col] =
                            a[r] + bb + res[(size_t)(row + r) * N + col];
                } else {
                    bf4 pv;
                    #pragma unroll
                    for (int r = 0; r < 4; ++r) pv.v[r] = __float2bfloat16(a[r] + bb);
                    *(bf4*)(vT + (size_t)(col - 2048) * M + row) = pv;
                }
            }
        }
    }
}

// ======================================================================
// 256x256 8-wave phase-interleaved GEMM, v6 = R4/R8 pinned form with
// SINGLE-BARRIER phases (m201's actual structure: 4 barriers/K-tile,
// not 8). Phase = {reads -> stage-issue -> counted vmcnt -> s_barrier
// -> lgkmcnt(0) -> setprio/MFMA}. The vmcnt sits BEFORE the barrier so
// every wave's staged data is landed before any wave's dependent reads
// (reads of phase p+1 occur after BARRIER_p).
// Hazard proof (rendezvous semantics, interval k = [BAR_{k-1},BAR_k]
// contains MFMA(k-1), reads(k), stage(k), VW(k)):
//  RAW: p0 reads g0/g1(t) <- VW@p3(t-1)+barrier; p1 reads g2(t) <-
//       VW2@p0; p2 reads g3(t) <- VW3@p1. All waits precede a barrier
//       that precedes the read.
//  WAR: stage(p0)=g2(t+1)->nb.A1, old read @p1(t-1), 3 barriers back;
//       stage(p1)=g3(t+1)->nb.Bq1, old read @p2(t-1), 3 back;
//       stage(p2)=g1(t+2)->cur.Bq0, old read @p0(t), 2 back;
//       stage(p3)=g0(t+2)->cur.A0, old read @p0(t), 3 back. All >= 2.
// vmcnt accounting identical to R4/R8 (issue order unchanged).
// MODE 1: gelu bf16 out. MODE 3: qkv (Q scaled, V -> vT transposed).
// ======================================================================

#define G8_BARRIER() do {                                   \
    __builtin_amdgcn_sched_barrier(0);                      \
    asm volatile("" ::: "memory");                          \
    __builtin_amdgcn_s_barrier();                           \
    asm volatile("" ::: "memory");                          \
    __builtin_amdgcn_sched_barrier(0);                      \
  } while (0)

#define G8_WAIT_LGKM0() do {                                        \
    asm volatile("s_waitcnt lgkmcnt(0)" ::: "memory");              \
    __builtin_amdgcn_sched_barrier(0);                              \
  } while (0)

#define G8_WAIT_VM(n) asm volatile("s_waitcnt vmcnt(" #n ")" ::: "memory")

#define G8_VW2() do { if (st1) G8_WAIT_VM(8); else G8_WAIT_VM(2); } while (0)
#define G8_VW3() do { if (st1) G8_WAIT_VM(8); else G8_WAIT_VM(0); } while (0)
#define G8_VW1() do { if (st2) G8_WAIT_VM(8); else if (st1) G8_WAIT_VM(4); \
                      else G8_WAIT_VM(0); } while (0)

#define G8_PHASE(Aq, Bq, RA, RB, SC, SG, DB, KO, VW)                           \
  do {                                                                         \
    if (RA) {                                                                  \
      const bf16* pa0 = smem + cur * BUF + aof0 + (Aq) * 8192;                 \
      const bf16* pa1 = smem + cur * BUF + aof1 + (Aq) * 8192;                 \
      _Pragma("unroll")                                                        \
      for (int i = 0; i < 4; ++i) {                                            \
        ar[Aq][i][0] = *(const bf16x8*)(pa0 + i * 1024);                       \
        ar[Aq][i][1] = *(const bf16x8*)(pa1 + i * 1024);                       \
      }                                                                        \
    }                                                                          \
    if (RB) {                                                                  \
      const bf16* pb0 = smem + cur * BUF + bof0 + (Bq) * 2048;                 \
      const bf16* pb1 = smem + cur * BUF + bof1 + (Bq) * 2048;                 \
      _Pragma("unroll")                                                        \
      for (int jj = 0; jj < 2; ++jj) {                                         \
        br[jj][0] = *(const bf16x8*)(pb0 + jj * 1024);                         \
        br[jj][1] = *(const bf16x8*)(pb1 + jj * 1024);                         \
      }                                                                        \
    }                                                                          \
    if (SC) {                                                                  \
      GLOAD_LDS16(gsrc[SG] + (KO), smem + (DB) * BUF + lof[SG]);               \
      GLOAD_LDS16(gsrc[SG] + (KO) + (((SG) & 1) ? gdB : gdA),                  \
                  smem + (DB) * BUF + lof[SG] + (((SG) & 1) ? 8192 : 4096));   \
    }                                                                          \
    VW;                                                                        \
    G8_BARRIER();                                                              \
    G8_WAIT_LGKM0();                                                           \
    __builtin_amdgcn_s_setprio(1);                                             \
    _Pragma("unroll")                                                          \
    for (int i = 0; i < 4; ++i)                                                \
      _Pragma("unroll")                                                        \
      for (int jj = 0; jj < 2; ++jj) {                                         \
        acc[(Aq)*4+i][(Bq)*2+jj] = __builtin_amdgcn_mfma_f32_16x16x32_bf16(    \
            ar[Aq][i][0], br[jj][0], acc[(Aq)*4+i][(Bq)*2+jj], 0, 0, 0);       \
        acc[(Aq)*4+i][(Bq)*2+jj] = __builtin_amdgcn_mfma_f32_16x16x32_bf16(    \
            ar[Aq][i][1], br[jj][1], acc[(Aq)*4+i][(Bq)*2+jj], 0, 0, 0);       \
      }                                                                        \
    __builtin_amdgcn_s_setprio(0);                                             \
  } while (0)

template<int MODE>
__global__ __launch_bounds__(512, 2) void gemm8_t(
    const bf16* __restrict__ A, const bf16* __restrict__ Wt,
    const float* __restrict__ bias, bf16* __restrict__ out,
    bf16* __restrict__ vT, int M, int N, int K)
{
    constexpr int BUF = 32768;                 // elems per dbuf (A 16K + B 16K)
    __shared__ __align__(16) bf16 smem[2 * BUF];   // 128 KiB

    const int tid = threadIdx.x;
    const int w = tid >> 6, l = tid & 63;
    const int fm = l & 15, qd = l >> 4;
    const int wm = w >> 2, wn = w & 3;         // 2 x 4 waves

    // XCD-aware bijective swizzle (nwg % 8 == 0 for all our grids)
    const int nbx = gridDim.x;
    const int nwg = nbx * gridDim.y;
    const int bid = blockIdx.y * nbx + blockIdx.x;
    const int cpx = nwg >> 3;
    const int swz = (bid & 7) * cpx + (bid >> 3);
    const int m0 = (swz % nbx) * 256;
    const int n0 = (swz / nbx) * 256;

    // ---- staging slots (even slot for c=tid; odd slot = +gdA/+gdB global,
    //      +4096/+8192 LDS): g0=A half0, g1=B q0-rows, g2=A half1, g3=B q1-rows
    const size_t gdA = (size_t)64 * K;         // A odd-slot: +64 rows
    const size_t gdB = (size_t)128 * K;        // B odd-slot: +128 rows
    const bf16* gsrc[4];
    int lof[4];
    #pragma unroll
    for (int g = 0; g < 4; ++g) {
        const int isB  = (g & 1);
        const int half = (g >> 1);
        const int pos = tid & 7;
        int row, lofe;
        const bf16* gb;
        if (!isB) {
            row  = half * 128 + (tid >> 3);
            gb   = A + (size_t)(m0 + row) * K;
            lofe = row * 64 + pos * 8;               // A region [0,16384)
        } else {
            const int vr = tid >> 3;
            row  = (vr >> 5) * 64 + half * 32 + (vr & 31);
            gb   = Wt + (size_t)(n0 + row) * K;
            lofe = 16384 + row * 64 + pos * 8;       // B region [16384,32768)
        }
        const int ch = pos ^ (row & 7);
        gsrc[g] = gb + ch * 8;
        lof[g]  = lofe;
    }

    // ---- fragment LDS offsets (swizzled chunk; row&7 == fm&7)
    const int sw0 = qd ^ (fm & 7);
    const int aof0 = (wm * 64 + fm) * 64 + sw0 * 8;
    const int aof1 = (wm * 64 + fm) * 64 + (sw0 ^ 4) * 8;
    const int bof0 = 16384 + (wn * 64 + fm) * 64 + sw0 * 8;
    const int bof1 = 16384 + (wn * 64 + fm) * 64 + (sw0 ^ 4) * 8;

    floatx4 acc[8][4] = {};
    bf16x8 ar[2][4][2];                        // A frags, both halves, resident
    bf16x8 br[2][2];                           // B frags, current Bq, resident

    // ---- prologue: g0(0),g1(0),g2(0),g3(0) -> buf0; g1(1),g0(1) -> buf1
    GLOAD_LDS16(gsrc[0],       smem + lof[0]);
    GLOAD_LDS16(gsrc[0] + gdA, smem + lof[0] + 4096);
    GLOAD_LDS16(gsrc[1],       smem + lof[1]);
    GLOAD_LDS16(gsrc[1] + gdB, smem + lof[1] + 8192);
    GLOAD_LDS16(gsrc[2],       smem + lof[2]);
    GLOAD_LDS16(gsrc[2] + gdA, smem + lof[2] + 4096);
    GLOAD_LDS16(gsrc[3],       smem + lof[3]);
    GLOAD_LDS16(gsrc[3] + gdB, smem + lof[3] + 8192);
    GLOAD_LDS16(gsrc[1] + 64,       smem + BUF + lof[1]);
    GLOAD_LDS16(gsrc[1] + 64 + gdB, smem + BUF + lof[1] + 8192);
    GLOAD_LDS16(gsrc[0] + 64,       smem + BUF + lof[0]);
    GLOAD_LDS16(gsrc[0] + 64 + gdA, smem + BUF + lof[0] + 4096);
    G8_WAIT_VM(8);                 // g0(0), g1(0) complete
    G8_BARRIER();

    const int nt = K / 64;
    int cur = 0;
    for (int t = 0; t < nt; ++t, cur ^= 1) {
        const bool st1 = (t + 1 < nt);
        const bool st2 = (t + 2 < nt);
        const int nb = cur ^ 1;
        const size_t ko1 = (size_t)(t + 1) * 64;
        const size_t ko2 = (size_t)(t + 2) * 64;
        G8_PHASE(0, 0, 1, 1, st1, 2, nb,  ko1, G8_VW2());   // stage g2(t+1)
        G8_PHASE(1, 0, 1, 0, st1, 3, nb,  ko1, G8_VW3());   // stage g3(t+1)
        G8_PHASE(0, 1, 0, 1, st2, 1, cur, ko2, ;);          // stage g1(t+2)
        G8_PHASE(1, 1, 0, 0, st2, 0, cur, ko2, G8_VW1());   // stage g0(t+2)
    }

    // ---- epilogue (smem reuse as per-wave bounce slots)
    G8_WAIT_VM(0);
    G8_BARRIER();

    const int colb = n0 + wn * 64;
    if (MODE == 3 && colb >= 2048) {
        // V: direct transposed store
        #pragma unroll
        for (int jf = 0; jf < 4; ++jf) {
            const int col = colb + jf * 16 + fm;
            const float bb = bias[col];
            #pragma unroll
            for (int f = 0; f < 8; ++f) {
                const int row = m0 + (f >> 2) * 128 + wm * 64 + (f & 3) * 16 + qd * 4;
                bf4 pv;
                #pragma unroll
                for (int r = 0; r < 4; ++r)
                    pv.v[r] = __float2bfloat16(acc[f][jf][r] + bb);
                *(bf4*)(vT + (size_t)(col - 2048) * M + row) = pv;
            }
        }
    } else {
        const float scale = (MODE == 3 && colb < 1024) ? 0.125f : 1.0f;
        bf16* eb = smem + w * 8192;            // 2 patches of 64x64 per wave
        #pragma unroll
        for (int jf = 0; jf < 4; ++jf) {
            const int col = colb + jf * 16 + fm;
            const float bb = bias[col];
            const int lc = jf * 16 + fm;
            const int pch = ((lc >> 3) + 2 * qd) & 7;
            #pragma unroll
            for (int f = 0; f < 8; ++f) {
                const int lr = (f & 3) * 16 + qd * 4;
                #pragma unroll
                for (int r = 0; r < 4; ++r) {
                    float vv = acc[f][jf][r] + bb;
                    if (MODE == 1) {
                        float zz = vv * (0.7978845608f + 0.0356774081f * vv * vv);
                        zz = fminf(zz, 15.0f);
                        const float e = __expf(2.0f * zz);
                        vv = vv * (e / (e + 1.0f));
                    }
                    vv *= scale;
                    eb[(f >> 2) * 4096 + (lr + r) * 64 + pch * 8 + (lc & 7)] =
                        __float2bfloat16(vv);
                }
            }
        }
        // wave-local readback -> 16B coalesced stores (compiler inserts lgkm waits)
        #pragma unroll
        for (int p = 0; p < 2; ++p)
            #pragma unroll
            for (int c = 0; c < 8; ++c) {
                const int idx = c * 64 + l;
                const int row = idx >> 3, c8 = idx & 7;
                const int pch = (c8 + 2 * ((row >> 2) & 3)) & 7;
                const bf16x8 vv = *(const bf16x8*)(eb + p * 4096 + row * 64 + pch * 8);
                const int rowg = m0 + p * 128 + wm * 64 + row;
                *(bf16x8*)(out + (size_t)rowg * N + colb + c8 * 8) = vv;
            }
    }
}

// ------------------------------------------------------- MFMA flash attention
__global__ __launch_bounds__(256) void attn_mfma_kernel(
    const bf16* __restrict__ qkv, const bf16* __restrict__ vT,
    bf16* __restrict__ y)
{
    const int pi = blockIdx.x, h = blockIdx.y, b = blockIdx.z;
    const int tid = threadIdx.x, w = tid >> 6, l = tid & 63;
    const int fm = l & 15, qd = l >> 4;
    const int qta = pi, qtb = 31 - pi;
    const float M0 = 3.0f;

    __shared__ __align__(16) bf16 Ks[4096];
    __shared__ __align__(16) bf16 Vs[4096];
    __shared__ __align__(16) bf16 Ps[8][1152];

    const int r0 = tid >> 2,         c0 = (tid & 3) ^ ((r0 >> 1) & 3);
    const int r1 = (tid + 256) >> 2, c1 = ((tid + 256) & 3) ^ ((r1 >> 1) & 3);
    const bf16* kbase = qkv + (size_t)(b * T_) * 3072 + 1024 + h * 64;
    const bf16* vbase = vT + (size_t)(h * 64) * BT_ + b * T_;
    const bf16* kg0 = kbase + (size_t)(r0 & 63) * 3072 + (r0 >> 6) * 32 + c0 * 8;
    const bf16* kg1 = kbase + (size_t)(r1 & 63) * 3072 + (r1 >> 6) * 32 + c1 * 8;
    const bf16* vg0 = vbase + (size_t)(r0 & 63) * BT_ + (r0 >> 6) * 32 + c0 * 8;
    const bf16* vg1 = vbase + (size_t)(r1 & 63) * BT_ + (r1 >> 6) * 32 + c1 * 8;
    bf16* ksl0 = Ks + (size_t)(w * 64) * 8;
    bf16* ksl1 = Ks + (size_t)(w * 64 + 256) * 8;
    bf16* vsl0 = Vs + (size_t)(w * 64) * 8;
    bf16* vsl1 = Vs + (size_t)(w * 64 + 256) * 8;

    const bf16* qpa = qkv + (size_t)(b * T_ + qta * 64 + w * 16 + fm) * 3072 + h * 64 + qd * 8;
    const bf16* qpb = qkv + (size_t)(b * T_ + qtb * 64 + w * 16 + fm) * 3072 + h * 64 + qd * 8;
    const bf16x8 qa0 = *(const bf16x8*)qpa, qa1 = *(const bf16x8*)(qpa + 32);
    const bf16x8 qb0 = *(const bf16x8*)qpb, qb1 = *(const bf16x8*)(qpb + 32);

    const int qba = qta * 64 + w * 16 + qd * 4;
    const int qbb = qtb * 64 + w * 16 + qd * 4;
    const int sw = (qd ^ ((fm >> 1) & 3)) * 8;

    float la[4] = {}, lb[4] = {};
    floatx4 Oa[4] = {}, Ob[4] = {};
    bf16* psa = &Ps[w * 2][0];
    bf16* psb = &Ps[w * 2 + 1][0];

    auto tile = [&](const bf16x8 q0, const bf16x8 q1, float* lsum,
                    floatx4* O, bf16* ps, const int kt, const int qt, const int qb) {
        floatx4 S[4];
        #pragma unroll
        for (int nt = 0; nt < 4; ++nt) {
            const int rr = nt * 16 + fm;
            const bf16x8 k0 = *(const bf16x8*)(Ks + rr * 32 + sw);
            const bf16x8 k1 = *(const bf16x8*)(Ks + (64 + rr) * 32 + sw);
            floatx4 s = {};
            s = __builtin_amdgcn_mfma_f32_16x16x32_bf16(q0, k0, s, 0, 0, 0);
            s = __builtin_amdgcn_mfma_f32_16x16x32_bf16(q1, k1, s, 0, 0, 0);
            S[nt] = s;
        }
        if (kt == qt) {
            #pragma unroll
            for (int nt = 0; nt < 4; ++nt) {
                const int key = kt * 64 + nt * 16 + fm;
                #pragma unroll
                for (int r = 0; r < 4; ++r)
                    if (key > qb + r) S[nt][r] = -1e30f;
            }
        }
        #pragma unroll
        for (int nt = 0; nt < 4; ++nt)
            #pragma unroll
            for (int r = 0; r < 4; ++r) {
                const float p = __expf(S[nt][r] - M0);
                lsum[r] += p;
                ps[(qd * 4 + r) * 72 + nt * 16 + fm] = __float2bfloat16(p);
            }
        #pragma unroll
        for (int s2 = 0; s2 < 2; ++s2) {
            const bf16x8 pf = *(const bf16x8*)(ps + fm * 72 + s2 * 32 + qd * 8);
            #pragma unroll
            for (int nt = 0; nt < 4; ++nt) {
                const bf16x8 vf =
                    *(const bf16x8*)(Vs + (s2 * 64 + nt * 16 + fm) * 32 + sw);
                O[nt] = __builtin_amdgcn_mfma_f32_16x16x32_bf16(pf, vf, O[nt], 0, 0, 0);
            }
        }
    };

    for (int kt = 0; kt <= qtb; ++kt) {
        const size_t kOff = (size_t)kt * 64 * 3072;
        const size_t vOff = (size_t)kt * 64;
        __syncthreads();
        GLOAD_LDS16(kg0 + kOff, ksl0);
        GLOAD_LDS16(kg1 + kOff, ksl1);
        GLOAD_LDS16(vg0 + vOff, vsl0);
        GLOAD_LDS16(vg1 + vOff, vsl1);
        __syncthreads();
        tile(qb0, qb1, lb, Ob, psb, kt, qtb, qbb);
        if (kt <= qta)
            tile(qa0, qa1, la, Oa, psa, kt, qta, qba);
    }

    #pragma unroll
    for (int mk = 1; mk < 16; mk <<= 1)
        #pragma unroll
        for (int r = 0; r < 4; ++r) {
            la[r] += __shfl_xor(la[r], mk);
            lb[r] += __shfl_xor(lb[r], mk);
        }

    #pragma unroll
    for (int r = 0; r < 4; ++r) {
        const float inva = 1.0f / la[r];
        const float invb = 1.0f / lb[r];
        const size_t rowa = (size_t)(b * T_) + qba + r;
        const size_t rowb = (size_t)(b * T_) + qbb + r;
        #pragma unroll
        for (int nt = 0; nt < 4; ++nt) {
            y[rowa * C_ + h * 64 + nt * 16 + fm] = __float2bfloat16(Oa[nt][r] * inva);
            y[rowb * C_ + h * 64 + nt * 16 + fm] = __float2bfloat16(Ob[nt][r] * invb);
        }
    }
}

// ------------------------------------------------------------------ launch
extern "C" void kernel_launch(void* const* d_in, const int* in_sizes, int n_in,
                              void* d_out, int out_size, void* d_ws, size_t ws_size,
                              hipStream_t stream)
{
    const float* x     = (const float*)d_in[0];
    const float* ln1_w = (const float*)d_in[1];
    const float* ln1_b = (const float*)d_in[2];
    const float* wq    = (const float*)d_in[3];
    const float* bq    = (const float*)d_in[4];
    const float* wk    = (const float*)d_in[5];
    const float* bk    = (const float*)d_in[6];
    const float* wv    = (const float*)d_in[7];
    const float* bv    = (const float*)d_in[8];
    const float* wo    = (const float*)d_in[9];
    const float* bo    = (const float*)d_in[10];
    const float* ln2_w = (const float*)d_in[11];
    const float* ln2_b = (const float*)d_in[12];
    const float* w1    = (const float*)d_in[13];
    const float* b1    = (const float*)d_in[14];
    const float* w2    = (const float*)d_in[15];
    const float* b2    = (const float*)d_in[16];
    float* out = (float*)d_out;

    char* ws = (char*)d_ws;
    const size_t MB = 1024 * 1024;
    bf16*  wqkvT = (bf16*)(ws);                      // 6 MB  (dead after qkv)
    bf16*  woT   = (bf16*)(ws + 6 * MB);             // 2 MB  (dead after proj)
    bf16*  w1T   = (bf16*)(ws + 8 * MB);             // 8 MB  (dead after mlp1)
    bf16*  w2T   = (bf16*)(ws + 16 * MB);            // 8 MB  (LIVE through mlp2)
    float* bqkv  = (float*)(ws + 24 * MB);           // 12 KB (64 KB slot)
    bf16*  h     = (bf16*)(ws + 24 * MB + 65536);    // 8 MB  (dead after mlp1)
    bf16*  qkv   = (bf16*)(ws + 32 * MB + 65536);    // 24 MB (dead after attn)
    bf16*  vT    = (bf16*)(ws + 56 * MB + 65536);    // 8 MB  (dead after attn)
    bf16*  y     = (bf16*)(ws + 64 * MB + 65536);    // 8 MB  (dead after proj)
    float* x2    = (float*)(ws + 72 * MB + 65536);   // 16 MB (live till mlp2)
    bf16*  u     = qkv;                              // 32 MB overlay (qkv+vT dead)
    float* p1    = (float*)ws;                       // 16 MB overlay [0,16MB):
                                                     // wqkvT/woT/w1T dead at mlp2
                                                     // (w2T at [16,24MB) untouched)

    // fused prologue: weight conversions + bias concat + ln1
    prep_kernel<<<7180, 256, 0, stream>>>(
        x, ln1_w, ln1_b, wq, wk, wv, wo, bq, bk, bv, w1, w2,
        h, wqkvT, woT, w1T, w2T, bqkv);

    // attention branch
    gemm8_t<3><<<dim3(16, 12), 512, 0, stream>>>(
        h, wqkvT, bqkv, qkv, vT, BT_, 3072, C_);
    attn_mfma_kernel<<<dim3(16, H_, B_), 256, 0, stream>>>(qkv, vT, y);
    mfma_gemm_t<128, 64, 64><<<dim3(32, 16), 256, 0, stream>>>(
        y, woT, bo, x, x2, nullptr, nullptr, BT_, C_, C_, C_, 2);

    // MLP branch
    ln_bf16_kernel<<<BT_, 256, 0, stream>>>(x2, ln2_w, ln2_b, h);
    gemm8_t<1><<<dim3(16, 16), 512, 0, stream>>>(
        h, w1T, b1, u, nullptr, BT_, 4 * C_, C_);
    // mlp2: split-K=2; z=0 -> out (+bias+res), z=1 -> p1; then out += p1
    mfma_gemm_t<128, 128, 64><<<dim3(32, 8, 2), 256, 0, stream>>>(
        u, w2T, b2, x2, out, nullptr, p1, BT_, C_, 2 * C_, 4 * C_, 4);
    splitk2_kernel<<<BT_ * C_ / 1024, 256, 0, stream>>>(out, p1);
}

// Round 14
// 334.199 us; speedup vs baseline: 1.0725x; 1.0725x over previous
//
#include <hip/hip_runtime.h>
#include <hip/hip_bf16.h>
#include <math.h>

#define B_  2
#define T_  2048
#define C_  1024
#define H_  16
#define D_  64
#define BT_ (B_*T_)

typedef __hip_bfloat16 bf16;
typedef short bf16x8 __attribute__((ext_vector_type(8)));
typedef float floatx4 __attribute__((ext_vector_type(4)));

struct alignas(8) bf4 { bf16 v[4]; };

#define GLOAD_LDS16(g, l) __builtin_amdgcn_global_load_lds(            \
    (const __attribute__((address_space(1))) void*)(g),                \
    (__attribute__((address_space(3))) void*)(l), 16, 0, 0)

// ---------------------------------------------------------------- LayerNorm body
__device__ __forceinline__ void ln_body(const float* __restrict__ x,
    const float* __restrict__ w, const float* __restrict__ b,
    bf16* __restrict__ out, const int row)
{
    __shared__ float ps[4], ps2[4];
    __shared__ float sm, srs;
    const int tid = threadIdx.x;
    float4 v = ((const float4*)(x + (size_t)row * C_))[tid];
    float s  = v.x + v.y + v.z + v.w;
    float s2 = v.x*v.x + v.y*v.y + v.z*v.z + v.w*v.w;
    for (int off = 32; off > 0; off >>= 1) {
        s  += __shfl_down(s,  off);
        s2 += __shfl_down(s2, off);
    }
    const int wid = tid >> 6;
    if ((tid & 63) == 0) { ps[wid] = s; ps2[wid] = s2; }
    __syncthreads();
    if (tid == 0) {
        float ts  = ps[0] + ps[1] + ps[2] + ps[3];
        float ts2 = ps2[0] + ps2[1] + ps2[2] + ps2[3];
        float mean = ts * (1.0f / C_);
        float var  = ts2 * (1.0f / C_) - mean * mean;
        sm  = mean;
        srs = rsqrtf(var + 1e-5f);
    }
    __syncthreads();
    const float mean = sm, rs = srs;
    float4 wv = ((const float4*)w)[tid];
    float4 bv = ((const float4*)b)[tid];
    bf4 o;
    o.v[0] = __float2bfloat16((v.x - mean) * rs * wv.x + bv.x);
    o.v[1] = __float2bfloat16((v.y - mean) * rs * wv.y + bv.y);
    o.v[2] = __float2bfloat16((v.z - mean) * rs * wv.z + bv.z);
    o.v[3] = __float2bfloat16((v.w - mean) * rs * wv.w + bv.w);
    *(bf4*)(out + (size_t)row * C_ + tid * 4) = o;
}

__global__ __launch_bounds__(256) void ln_bf16_kernel(const float* __restrict__ x,
    const float* __restrict__ w, const float* __restrict__ b,
    bf16* __restrict__ out)
{
    ln_body(x, w, b, out, blockIdx.x);
}

// ------------------------------------------- weight fp32 [K][N] -> bf16 [N][K]
__device__ __forceinline__ void wconv_body(const float* __restrict__ W,
    bf16* __restrict__ Wt, int K, int N, int k0, int n0)
{
    __shared__ float L[64][65];
    const int t = threadIdx.x;
    const int r = t >> 4, c4 = t & 15;
    #pragma unroll
    for (int p = 0; p < 4; ++p) {
        const int kr = p * 16 + r;
        const float4 v = *(const float4*)(W + (size_t)(k0 + kr) * N + n0 + c4 * 4);
        L[kr][c4*4+0] = v.x; L[kr][c4*4+1] = v.y;
        L[kr][c4*4+2] = v.z; L[kr][c4*4+3] = v.w;
    }
    __syncthreads();
    #pragma unroll
    for (int p = 0; p < 4; ++p) {
        const int nr = p * 16 + r;
        bf4 o;
        o.v[0] = __float2bfloat16(L[c4*4+0][nr]);
        o.v[1] = __float2bfloat16(L[c4*4+1][nr]);
        o.v[2] = __float2bfloat16(L[c4*4+2][nr]);
        o.v[3] = __float2bfloat16(L[c4*4+3][nr]);
        *(bf4*)(Wt + (size_t)(n0 + nr) * K + k0 + c4 * 4) = o;
    }
}

// ---------------------------------------------------------- fused prologue
// flat grid, range-decoded:
//   [0,1024):    wconv4 (wq/wk/wv/wo -> wqkvT/woT), 16x16x4
//   [1024,3072): wconv2 (w1 -> w1T, w2 -> w2T), 16x64x2
//   [3072,7168): ln1 (x -> h), 4096 rows
//   [7168,7180): bias concat bq|bk|bv -> bqkv
__global__ __launch_bounds__(256) void prep_kernel(
    const float* __restrict__ x, const float* __restrict__ ln1_w,
    const float* __restrict__ ln1_b,
    const float* __restrict__ wq, const float* __restrict__ wk,
    const float* __restrict__ wv, const float* __restrict__ wo,
    const float* __restrict__ bq, const float* __restrict__ bk,
    const float* __restrict__ bv,
    const float* __restrict__ w1, const float* __restrict__ w2,
    bf16* __restrict__ h, bf16* __restrict__ wqkvT, bf16* __restrict__ woT,
    bf16* __restrict__ w1T, bf16* __restrict__ w2T,
    float* __restrict__ bqkv)
{
    const int b = blockIdx.x;
    if (b < 1024) {
        const int z = b >> 8, rem = b & 255;
        const float* W = (z == 0) ? wq : (z == 1) ? wk : (z == 2) ? wv : wo;
        bf16* Wt = (z == 3) ? woT : wqkvT + (size_t)z * 1024 * 1024;
        wconv_body(W, Wt, 1024, 1024, (rem & 15) * 64, (rem >> 4) * 64);
    } else if (b < 3072) {
        const int c = b - 1024, z = c >> 10, r = c & 1023;
        if (z == 0) wconv_body(w1, w1T, 1024, 4096, (r & 15) * 64, (r >> 4) * 64);
        else        wconv_body(w2, w2T, 4096, 1024, (r >> 4) * 64, (r & 15) * 64);
    } else if (b < 7168) {
        ln_body(x, ln1_w, ln1_b, h, b - 3072);
    } else {
        const int i = (b - 7168) * 256 + threadIdx.x;
        float v = (i < 1024) ? bq[i] : (i < 2048 ? bk[i - 1024] : bv[i - 2048]);
        bqkv[i] = v;
    }
}

// ----------------------------------------------------- split-K reduce (mlp2)
// out = out(raw z0 partial) + p1(raw z1 partial) + bias + res  (R4/R5 form:
// coalesced float4 traffic here beats scattered res-reads in the GEMM
// epilogue — measured mlp2 slot 52-54 vs 58.5-60)
__global__ __launch_bounds__(256) void splitk_reduce_kernel(
    float* __restrict__ out, const float* __restrict__ p1,
    const float* __restrict__ bias, const float* __restrict__ res)
{
    const size_t i = (size_t)blockIdx.x * 256 + threadIdx.x;   // float4 idx
    float4 o = ((const float4*)out)[i];
    const float4 p = ((const float4*)p1)[i];
    const float4 bb = ((const float4*)bias)[i & (C_ / 4 - 1)];
    const float4 xx = ((const float4*)res)[i];
    o.x += p.x + bb.x + xx.x;
    o.y += p.y + bb.y + xx.y;
    o.z += p.z + bb.z + xx.z;
    o.w += p.w + bb.w + xx.w;
    ((float4*)out)[i] = o;
}

// -------------------------------------------------------------- MFMA GEMM (old 2-barrier 128-tile)
// kept for proj (mode 2) and mlp2 split-K (mode 4, raw partials)
template<int TM, int TN, int BK>
__global__ __launch_bounds__(256) void mfma_gemm_t(
    const bf16* __restrict__ A, const bf16* __restrict__ Wt,
    const float* __restrict__ bias, const float* __restrict__ res,
    void* __restrict__ outv, bf16* __restrict__ vT, float* __restrict__ psplit,
    int M, int N, int K, int ldk, int mode)
{
    constexpr int MI = TM / 32;
    constexpr int NJ = TN / 32;
    constexpr int CPR = BK / 8;                       // 16B chunks per row
    constexpr int NSLOT = (TM + TN) * CPR / 256;
    __shared__ __align__(16) bf16 smem[(TM + TN) * BK];
    bf16* As = smem;
    bf16* Bs = smem + TM * BK;
    const int tid = threadIdx.x;
    const int w = tid >> 6, l = tid & 63;
    const int fm = l & 15, qd = l >> 4;
    const int m0 = blockIdx.x * TM, n0 = blockIdx.y * TN;
    const int bz = blockIdx.z;
    const int wr = (w >> 1) * (TM / 2), wc = (w & 1) * (TN / 2);

    const bf16* Ab = A  + (size_t)bz * K;
    const bf16* Wb = Wt + (size_t)bz * K;

    const bf16* gsrc[NSLOT];
    bf16* ldst[NSLOT];
    #pragma unroll
    for (int p = 0; p < NSLOT; ++p) {
        const int s = tid + p * 256;
        if (s < TM * CPR) {
            const int row = s / CPR, pos = s % CPR;
            const int ch = pos ^ (row & (CPR - 1));
            gsrc[p] = Ab + (size_t)(m0 + row) * ldk + ch * 8;
            ldst[p] = As + s * 8;
        } else {
            const int s2 = s - TM * CPR;
            const int row = s2 / CPR, pos = s2 % CPR;
            const int ch = pos ^ (row & (CPR - 1));
            gsrc[p] = Wb + (size_t)(n0 + row) * ldk + ch * 8;
            ldst[p] = Bs + s2 * 8;
        }
    }

    floatx4 acc[MI][NJ] = {};

    const int nk = K / BK;
    for (int kk = 0; kk < nk; ++kk) {
        const size_t ko = (size_t)kk * BK;
        __syncthreads();
        #pragma unroll
        for (int p = 0; p < NSLOT; ++p)
            GLOAD_LDS16(gsrc[p] + ko, ldst[p]);
        __syncthreads();
        #pragma unroll
        for (int ks = 0; ks < BK / 32; ++ks) {
            bf16x8 af[MI], bfr[NJ];
            #pragma unroll
            for (int i = 0; i < MI; ++i) {
                const int row = wr + i * 16 + fm;
                af[i] = *(const bf16x8*)(As + row * BK
                        + (((ks * 4 + qd) ^ (row & (CPR - 1))) * 8));
            }
            #pragma unroll
            for (int j = 0; j < NJ; ++j) {
                const int row = wc + j * 16 + fm;
                bfr[j] = *(const bf16x8*)(Bs + row * BK
                        + (((ks * 4 + qd) ^ (row & (CPR - 1))) * 8));
            }
            #pragma unroll
            for (int i = 0; i < MI; ++i)
                #pragma unroll
                for (int j = 0; j < NJ; ++j)
                    acc[i][j] = __builtin_amdgcn_mfma_f32_16x16x32_bf16(
                        af[i], bfr[j], acc[i][j], 0, 0, 0);
        }
    }

    const int col0 = n0 + wc;
    const int row0 = m0 + wr;
    const bool isv = (mode == 3) && (col0 >= 2048);
    const bool bounce = (mode == 0) || (mode == 1) || (mode == 3 && !isv);
    __syncthreads();

    if (bounce) {
        constexpr int RM = TM / 2, RN = TN / 2, CHN = RN / 8;
        bf16* eb = smem + w * (RM * RN);
        #pragma unroll
        for (int j = 0; j < NJ; ++j) {
            const int col = col0 + j * 16 + fm;
            const float bb = bias[col];
            const bool isq = (mode == 3) && (col0 + j * 16 < 1024);
            const int lc = j * 16 + fm;
            #pragma unroll
            for (int i = 0; i < MI; ++i) {
                floatx4 a = acc[i][j];
                #pragma unroll
                for (int r = 0; r < 4; ++r) {
                    float vv = a[r] + bb;
                    if (mode == 1) {
                        float zz = vv * (0.7978845608f + 0.0356774081f * vv * vv);
                        zz = fminf(zz, 15.0f);
                        const float e = __expf(2.0f * zz);
                        vv = vv * (e / (e + 1.0f));
                    }
                    if (isq) vv *= 0.125f;
                    const int lr = i * 16 + qd * 4 + r;
                    const int pch = ((lc >> 3) + 2 * qd) & (CHN - 1);
                    eb[lr * RN + pch * 8 + (lc & 7)] = __float2bfloat16(vv);
                }
            }
        }
        bf16* o = (bf16*)outv;
        #pragma unroll
        for (int c = 0; c < RM * RN / 512; ++c) {
            const int idx = c * 64 + l;
            const int row = idx / CHN;
            const int c8  = idx % CHN;
            const int pch = (c8 + 2 * ((row >> 2) & 3)) & (CHN - 1);
            const bf16x8 vv = *(const bf16x8*)(eb + row * RN + pch * 8);
            *(bf16x8*)(o + (size_t)(row0 + row) * N + col0 + c8 * 8) = vv;
        }
    } else {
        #pragma unroll
        for (int j = 0; j < NJ; ++j) {
            const int col = col0 + j * 16 + fm;
            const float bb = bias[col];
            #pragma unroll
            for (int i = 0; i < MI; ++i) {
                const int row = row0 + i * 16 + qd * 4;
                floatx4 a = acc[i][j];
                if (mode == 4) {
                    // split-K raw partials: z=0 -> out, z=1 -> p1
                    float* o = bz ? psplit : (float*)outv;
                    #pragma unroll
                    for (int r = 0; r < 4; ++r)
                        o[(size_t)(row + r) * N + col] = a[r];
                } else if (mode == 2) {
                    float* o = (float*)outv;
                    #pragma unroll
                    for (int r = 0; r < 4; ++r)
                        o[(size_t)(row + r) * N + col] =
                            a[r] + bb + res[(size_t)(row + r) * N + col];
                } else {
                    bf4 pv;
                    #pragma unroll
                    for (int r = 0; r < 4; ++r) pv.v[r] = __float2bfloat16(a[r] + bb);
                    *(bf4*)(vT + (size_t)(col - 2048) * M + row) = pv;
                }
            }
        }
    }
}

// ======================================================================
// 256x256 8-wave phase-interleaved GEMM (R9 single-barrier pinned form,
// unchanged — measured best).
// ======================================================================

#define G8_BARRIER() do {                                   \
    __builtin_amdgcn_sched_barrier(0);                      \
    asm volatile("" ::: "memory");                          \
    __builtin_amdgcn_s_barrier();                           \
    asm volatile("" ::: "memory");                          \
    __builtin_amdgcn_sched_barrier(0);                      \
  } while (0)

#define G8_WAIT_LGKM0() do {                                        \
    asm volatile("s_waitcnt lgkmcnt(0)" ::: "memory");              \
    __builtin_amdgcn_sched_barrier(0);                              \
  } while (0)

#define G8_WAIT_VM(n) asm volatile("s_waitcnt vmcnt(" #n ")" ::: "memory")

#define G8_VW2() do { if (st1) G8_WAIT_VM(8); else G8_WAIT_VM(2); } while (0)
#define G8_VW3() do { if (st1) G8_WAIT_VM(8); else G8_WAIT_VM(0); } while (0)
#define G8_VW1() do { if (st2) G8_WAIT_VM(8); else if (st1) G8_WAIT_VM(4); \
                      else G8_WAIT_VM(0); } while (0)

#define G8_PHASE(Aq, Bq, RA, RB, SC, SG, DB, KO, VW)                           \
  do {                                                                         \
    if (RA) {                                                                  \
      const bf16* pa0 = smem + cur * BUF + aof0 + (Aq) * 8192;                 \
      const bf16* pa1 = smem + cur * BUF + aof1 + (Aq) * 8192;                 \
      _Pragma("unroll")                                                        \
      for (int i = 0; i < 4; ++i) {                                            \
        ar[Aq][i][0] = *(const bf16x8*)(pa0 + i * 1024);                       \
        ar[Aq][i][1] = *(const bf16x8*)(pa1 + i * 1024);                       \
      }                                                                        \
    }                                                                          \
    if (RB) {                                                                  \
      const bf16* pb0 = smem + cur * BUF + bof0 + (Bq) * 2048;                 \
      const bf16* pb1 = smem + cur * BUF + bof1 + (Bq) * 2048;                 \
      _Pragma("unroll")                                                        \
      for (int jj = 0; jj < 2; ++jj) {                                         \
        br[jj][0] = *(const bf16x8*)(pb0 + jj * 1024);                         \
        br[jj][1] = *(const bf16x8*)(pb1 + jj * 1024);                         \
      }                                                                        \
    }                                                                          \
    if (SC) {                                                                  \
      GLOAD_LDS16(gsrc[SG] + (KO), smem + (DB) * BUF + lof[SG]);               \
      GLOAD_LDS16(gsrc[SG] + (KO) + (((SG) & 1) ? gdB : gdA),                  \
                  smem + (DB) * BUF + lof[SG] + (((SG) & 1) ? 8192 : 4096));   \
    }                                                                          \
    VW;                                                                        \
    G8_BARRIER();                                                              \
    G8_WAIT_LGKM0();                                                           \
    __builtin_amdgcn_s_setprio(1);                                             \
    _Pragma("unroll")                                                          \
    for (int i = 0; i < 4; ++i)                                                \
      _Pragma("unroll")                                                        \
      for (int jj = 0; jj < 2; ++jj) {                                         \
        acc[(Aq)*4+i][(Bq)*2+jj] = __builtin_amdgcn_mfma_f32_16x16x32_bf16(    \
            ar[Aq][i][0], br[jj][0], acc[(Aq)*4+i][(Bq)*2+jj], 0, 0, 0);       \
        acc[(Aq)*4+i][(Bq)*2+jj] = __builtin_amdgcn_mfma_f32_16x16x32_bf16(    \
            ar[Aq][i][1], br[jj][1], acc[(Aq)*4+i][(Bq)*2+jj], 0, 0, 0);       \
      }                                                                        \
    __builtin_amdgcn_s_setprio(0);                                             \
  } while (0)

template<int MODE>
__global__ __launch_bounds__(512, 2) void gemm8_t(
    const bf16* __restrict__ A, const bf16* __restrict__ Wt,
    const float* __restrict__ bias, bf16* __restrict__ out,
    bf16* __restrict__ vT, int M, int N, int K)
{
    constexpr int BUF = 32768;                 // elems per dbuf (A 16K + B 16K)
    __shared__ __align__(16) bf16 smem[2 * BUF];   // 128 KiB

    const int tid = threadIdx.x;
    const int w = tid >> 6, l = tid & 63;
    const int fm = l & 15, qd = l >> 4;
    const int wm = w >> 2, wn = w & 3;         // 2 x 4 waves

    // XCD-aware bijective swizzle (nwg % 8 == 0 for all our grids)
    const int nbx = gridDim.x;
    const int nwg = nbx * gridDim.y;
    const int bid = blockIdx.y * nbx + blockIdx.x;
    const int cpx = nwg >> 3;
    const int swz = (bid & 7) * cpx + (bid >> 3);
    const int m0 = (swz % nbx) * 256;
    const int n0 = (swz / nbx) * 256;

    // ---- staging slots (even slot for c=tid; odd slot = +gdA/+gdB global,
    //      +4096/+8192 LDS): g0=A half0, g1=B q0-rows, g2=A half1, g3=B q1-rows
    const size_t gdA = (size_t)64 * K;         // A odd-slot: +64 rows
    const size_t gdB = (size_t)128 * K;        // B odd-slot: +128 rows
    const bf16* gsrc[4];
    int lof[4];
    #pragma unroll
    for (int g = 0; g < 4; ++g) {
        const int isB  = (g & 1);
        const int half = (g >> 1);
        const int pos = tid & 7;
        int row, lofe;
        const bf16* gb;
        if (!isB) {
            row  = half * 128 + (tid >> 3);
            gb   = A + (size_t)(m0 + row) * K;
            lofe = row * 64 + pos * 8;               // A region [0,16384)
        } else {
            const int vr = tid >> 3;
            row  = (vr >> 5) * 64 + half * 32 + (vr & 31);
            gb   = Wt + (size_t)(n0 + row) * K;
            lofe = 16384 + row * 64 + pos * 8;       // B region [16384,32768)
        }
        const int ch = pos ^ (row & 7);
        gsrc[g] = gb + ch * 8;
        lof[g]  = lofe;
    }

    // ---- fragment LDS offsets (swizzled chunk; row&7 == fm&7)
    const int sw0 = qd ^ (fm & 7);
    const int aof0 = (wm * 64 + fm) * 64 + sw0 * 8;
    const int aof1 = (wm * 64 + fm) * 64 + (sw0 ^ 4) * 8;
    const int bof0 = 16384 + (wn * 64 + fm) * 64 + sw0 * 8;
    const int bof1 = 16384 + (wn * 64 + fm) * 64 + (sw0 ^ 4) * 8;

    floatx4 acc[8][4] = {};
    bf16x8 ar[2][4][2];                        // A frags, both halves, resident
    bf16x8 br[2][2];                           // B frags, current Bq, resident

    // ---- prologue: g0(0),g1(0),g2(0),g3(0) -> buf0; g1(1),g0(1) -> buf1
    GLOAD_LDS16(gsrc[0],       smem + lof[0]);
    GLOAD_LDS16(gsrc[0] + gdA, smem + lof[0] + 4096);
    GLOAD_LDS16(gsrc[1],       smem + lof[1]);
    GLOAD_LDS16(gsrc[1] + gdB, smem + lof[1] + 8192);
    GLOAD_LDS16(gsrc[2],       smem + lof[2]);
    GLOAD_LDS16(gsrc[2] + gdA, smem + lof[2] + 4096);
    GLOAD_LDS16(gsrc[3],       smem + lof[3]);
    GLOAD_LDS16(gsrc[3] + gdB, smem + lof[3] + 8192);
    GLOAD_LDS16(gsrc[1] + 64,       smem + BUF + lof[1]);
    GLOAD_LDS16(gsrc[1] + 64 + gdB, smem + BUF + lof[1] + 8192);
    GLOAD_LDS16(gsrc[0] + 64,       smem + BUF + lof[0]);
    GLOAD_LDS16(gsrc[0] + 64 + gdA, smem + BUF + lof[0] + 4096);
    G8_WAIT_VM(8);                 // g0(0), g1(0) complete
    G8_BARRIER();

    const int nt = K / 64;
    int cur = 0;
    for (int t = 0; t < nt; ++t, cur ^= 1) {
        const bool st1 = (t + 1 < nt);
        const bool st2 = (t + 2 < nt);
        const int nb = cur ^ 1;
        const size_t ko1 = (size_t)(t + 1) * 64;
        const size_t ko2 = (size_t)(t + 2) * 64;
        G8_PHASE(0, 0, 1, 1, st1, 2, nb,  ko1, G8_VW2());   // stage g2(t+1)
        G8_PHASE(1, 0, 1, 0, st1, 3, nb,  ko1, G8_VW3());   // stage g3(t+1)
        G8_PHASE(0, 1, 0, 1, st2, 1, cur, ko2, ;);          // stage g1(t+2)
        G8_PHASE(1, 1, 0, 0, st2, 0, cur, ko2, G8_VW1());   // stage g0(t+2)
    }

    // ---- epilogue (smem reuse as per-wave bounce slots)
    G8_WAIT_VM(0);
    G8_BARRIER();

    const int colb = n0 + wn * 64;
    if (MODE == 3 && colb >= 2048) {
        // V: direct transposed store
        #pragma unroll
        for (int jf = 0; jf < 4; ++jf) {
            const int col = colb + jf * 16 + fm;
            const float bb = bias[col];
            #pragma unroll
            for (int f = 0; f < 8; ++f) {
                const int row = m0 + (f >> 2) * 128 + wm * 64 + (f & 3) * 16 + qd * 4;
                bf4 pv;
                #pragma unroll
                for (int r = 0; r < 4; ++r)
                    pv.v[r] = __float2bfloat16(acc[f][jf][r] + bb);
                *(bf4*)(vT + (size_t)(col - 2048) * M + row) = pv;
            }
        }
    } else {
        const float scale = (MODE == 3 && colb < 1024) ? 0.125f : 1.0f;
        bf16* eb = smem + w * 8192;            // 2 patches of 64x64 per wave
        #pragma unroll
        for (int jf = 0; jf < 4; ++jf) {
            const int col = colb + jf * 16 + fm;
            const float bb = bias[col];
            const int lc = jf * 16 + fm;
            const int pch = ((lc >> 3) + 2 * qd) & 7;
            #pragma unroll
            for (int f = 0; f < 8; ++f) {
                const int lr = (f & 3) * 16 + qd * 4;
                #pragma unroll
                for (int r = 0; r < 4; ++r) {
                    float vv = acc[f][jf][r] + bb;
                    if (MODE == 1) {
                        float zz = vv * (0.7978845608f + 0.0356774081f * vv * vv);
                        zz = fminf(zz, 15.0f);
                        const float e = __expf(2.0f * zz);
                        vv = vv * (e / (e + 1.0f));
                    }
                    vv *= scale;
                    eb[(f >> 2) * 4096 + (lr + r) * 64 + pch * 8 + (lc & 7)] =
                        __float2bfloat16(vv);
                }
            }
        }
        // wave-local readback -> 16B coalesced stores (compiler inserts lgkm waits)
        #pragma unroll
        for (int p = 0; p < 2; ++p)
            #pragma unroll
            for (int c = 0; c < 8; ++c) {
                const int idx = c * 64 + l;
                const int row = idx >> 3, c8 = idx & 7;
                const int pch = (c8 + 2 * ((row >> 2) & 3)) & 7;
                const bf16x8 vv = *(const bf16x8*)(eb + p * 4096 + row * 64 + pch * 8);
                const int rowg = m0 + p * 128 + wm * 64 + row;
                *(bf16x8*)(out + (size_t)rowg * N + colb + c8 * 8) = vv;
            }
    }
}

// ------------------------------------------------------- MFMA flash attention
// (R9 version — measured best; the counted-vmcnt double-buffer variant
// regressed +6us: attn's per-tile compute is too short to amortize the
// heavier pinned-barrier sync.)
__global__ __launch_bounds__(256) void attn_mfma_kernel(
    const bf16* __restrict__ qkv, const bf16* __restrict__ vT,
    bf16* __restrict__ y)
{
    const int pi = blockIdx.x, h = blockIdx.y, b = blockIdx.z;
    const int tid = threadIdx.x, w = tid >> 6, l = tid & 63;
    const int fm = l & 15, qd = l >> 4;
    const int qta = pi, qtb = 31 - pi;
    const float M0 = 3.0f;

    __shared__ __align__(16) bf16 Ks[4096];
    __shared__ __align__(16) bf16 Vs[4096];
    __shared__ __align__(16) bf16 Ps[8][1152];

    const int r0 = tid >> 2,         c0 = (tid & 3) ^ ((r0 >> 1) & 3);
    const int r1 = (tid + 256) >> 2, c1 = ((tid + 256) & 3) ^ ((r1 >> 1) & 3);
    const bf16* kbase = qkv + (size_t)(b * T_) * 3072 + 1024 + h * 64;
    const bf16* vbase = vT + (size_t)(h * 64) * BT_ + b * T_;
    const bf16* kg0 = kbase + (size_t)(r0 & 63) * 3072 + (r0 >> 6) * 32 + c0 * 8;
    const bf16* kg1 = kbase + (size_t)(r1 & 63) * 3072 + (r1 >> 6) * 32 + c1 * 8;
    const bf16* vg0 = vbase + (size_t)(r0 & 63) * BT_ + (r0 >> 6) * 32 + c0 * 8;
    const bf16* vg1 = vbase + (size_t)(r1 & 63) * BT_ + (r1 >> 6) * 32 + c1 * 8;
    bf16* ksl0 = Ks + (size_t)(w * 64) * 8;
    bf16* ksl1 = Ks + (size_t)(w * 64 + 256) * 8;
    bf16* vsl0 = Vs + (size_t)(w * 64) * 8;
    bf16* vsl1 = Vs + (size_t)(w * 64 + 256) * 8;

    const bf16* qpa = qkv + (size_t)(b * T_ + qta * 64 + w * 16 + fm) * 3072 + h * 64 + qd * 8;
    const bf16* qpb = qkv + (size_t)(b * T_ + qtb * 64 + w * 16 + fm) * 3072 + h * 64 + qd * 8;
    const bf16x8 qa0 = *(const bf16x8*)qpa, qa1 = *(const bf16x8*)(qpa + 32);
    const bf16x8 qb0 = *(const bf16x8*)qpb, qb1 = *(const bf16x8*)(qpb + 32);

    const int qba = qta * 64 + w * 16 + qd * 4;
    const int qbb = qtb * 64 + w * 16 + qd * 4;
    const int sw = (qd ^ ((fm >> 1) & 3)) * 8;

    float la[4] = {}, lb[4] = {};
    floatx4 Oa[4] = {}, Ob[4] = {};
    bf16* psa = &Ps[w * 2][0];
    bf16* psb = &Ps[w * 2 + 1][0];

    auto tile = [&](const bf16x8 q0, const bf16x8 q1, float* lsum,
                    floatx4* O, bf16* ps, const int kt, const int qt, const int qb) {
        floatx4 S[4];
        #pragma unroll
        for (int nt = 0; nt < 4; ++nt) {
            const int rr = nt * 16 + fm;
            const bf16x8 k0 = *(const bf16x8*)(Ks + rr * 32 + sw);
            const bf16x8 k1 = *(const bf16x8*)(Ks + (64 + rr) * 32 + sw);
            floatx4 s = {};
            s = __builtin_amdgcn_mfma_f32_16x16x32_bf16(q0, k0, s, 0, 0, 0);
            s = __builtin_amdgcn_mfma_f32_16x16x32_bf16(q1, k1, s, 0, 0, 0);
            S[nt] = s;
        }
        if (kt == qt) {
            #pragma unroll
            for (int nt = 0; nt < 4; ++nt) {
                const int key = kt * 64 + nt * 16 + fm;
                #pragma unroll
                for (int r = 0; r < 4; ++r)
                    if (key > qb + r) S[nt][r] = -1e30f;
            }
        }
        #pragma unroll
        for (int nt = 0; nt < 4; ++nt)
            #pragma unroll
            for (int r = 0; r < 4; ++r) {
                const float p = __expf(S[nt][r] - M0);
                lsum[r] += p;
                ps[(qd * 4 + r) * 72 + nt * 16 + fm] = __float2bfloat16(p);
            }
        #pragma unroll
        for (int s2 = 0; s2 < 2; ++s2) {
            const bf16x8 pf = *(const bf16x8*)(ps + fm * 72 + s2 * 32 + qd * 8);
            #pragma unroll
            for (int nt = 0; nt < 4; ++nt) {
                const bf16x8 vf =
                    *(const bf16x8*)(Vs + (s2 * 64 + nt * 16 + fm) * 32 + sw);
                O[nt] = __builtin_amdgcn_mfma_f32_16x16x32_bf16(pf, vf, O[nt], 0, 0, 0);
            }
        }
    };

    for (int kt = 0; kt <= qtb; ++kt) {
        const size_t kOff = (size_t)kt * 64 * 3072;
        const size_t vOff = (size_t)kt * 64;
        __syncthreads();
        GLOAD_LDS16(kg0 + kOff, ksl0);
        GLOAD_LDS16(kg1 + kOff, ksl1);
        GLOAD_LDS16(vg0 + vOff, vsl0);
        GLOAD_LDS16(vg1 + vOff, vsl1);
        __syncthreads();
        tile(qb0, qb1, lb, Ob, psb, kt, qtb, qbb);
        if (kt <= qta)
            tile(qa0, qa1, la, Oa, psa, kt, qta, qba);
    }

    #pragma unroll
    for (int mk = 1; mk < 16; mk <<= 1)
        #pragma unroll
        for (int r = 0; r < 4; ++r) {
            la[r] += __shfl_xor(la[r], mk);
            lb[r] += __shfl_xor(lb[r], mk);
        }

    #pragma unroll
    for (int r = 0; r < 4; ++r) {
        const float inva = 1.0f / la[r];
        const float invb = 1.0f / lb[r];
        const size_t rowa = (size_t)(b * T_) + qba + r;
        const size_t rowb = (size_t)(b * T_) + qbb + r;
        #pragma unroll
        for (int nt = 0; nt < 4; ++nt) {
            y[rowa * C_ + h * 64 + nt * 16 + fm] = __float2bfloat16(Oa[nt][r] * inva);
            y[rowb * C_ + h * 64 + nt * 16 + fm] = __float2bfloat16(Ob[nt][r] * invb);
        }
    }
}

// ------------------------------------------------------------------ launch
extern "C" void kernel_launch(void* const* d_in, const int* in_sizes, int n_in,
                              void* d_out, int out_size, void* d_ws, size_t ws_size,
                              hipStream_t stream)
{
    const float* x     = (const float*)d_in[0];
    const float* ln1_w = (const float*)d_in[1];
    const float* ln1_b = (const float*)d_in[2];
    const float* wq    = (const float*)d_in[3];
    const float* bq    = (const float*)d_in[4];
    const float* wk    = (const float*)d_in[5];
    const float* bk    = (const float*)d_in[6];
    const float* wv    = (const float*)d_in[7];
    const float* bv    = (const float*)d_in[8];
    const float* wo    = (const float*)d_in[9];
    const float* bo    = (const float*)d_in[10];
    const float* ln2_w = (const float*)d_in[11];
    const float* ln2_b = (const float*)d_in[12];
    const float* w1    = (const float*)d_in[13];
    const float* b1    = (const float*)d_in[14];
    const float* w2    = (const float*)d_in[15];
    const float* b2    = (const float*)d_in[16];
    float* out = (float*)d_out;

    char* ws = (char*)d_ws;
    const size_t MB = 1024 * 1024;
    bf16*  wqkvT = (bf16*)(ws);                      // 6 MB  (dead after qkv)
    bf16*  woT   = (bf16*)(ws + 6 * MB);             // 2 MB  (dead after proj)
    bf16*  w1T   = (bf16*)(ws + 8 * MB);             // 8 MB  (dead after mlp1)
    bf16*  w2T   = (bf16*)(ws + 16 * MB);            // 8 MB  (LIVE through mlp2)
    float* bqkv  = (float*)(ws + 24 * MB);           // 12 KB (64 KB slot)
    bf16*  h     = (bf16*)(ws + 24 * MB + 65536);    // 8 MB  (dead after mlp1)
    bf16*  qkv   = (bf16*)(ws + 32 * MB + 65536);    // 24 MB (dead after attn)
    bf16*  vT    = (bf16*)(ws + 56 * MB + 65536);    // 8 MB  (dead after attn)
    bf16*  y     = (bf16*)(ws + 64 * MB + 65536);    // 8 MB  (dead after proj)
    float* x2    = (float*)(ws + 72 * MB + 65536);   // 16 MB (live till reduce)
    bf16*  u     = qkv;                              // 32 MB overlay (qkv+vT dead)
    float* p1    = (float*)ws;                       // 16 MB overlay [0,16MB):
                                                     // wqkvT/woT/w1T dead at mlp2
                                                     // (w2T at [16,24MB) untouched)

    // fused prologue: weight conversions + bias concat + ln1
    prep_kernel<<<7180, 256, 0, stream>>>(
        x, ln1_w, ln1_b, wq, wk, wv, wo, bq, bk, bv, w1, w2,
        h, wqkvT, woT, w1T, w2T, bqkv);

    // attention branch
    gemm8_t<3><<<dim3(16, 12), 512, 0, stream>>>(
        h, wqkvT, bqkv, qkv, vT, BT_, 3072, C_);
    attn_mfma_kernel<<<dim3(16, H_, B_), 256, 0, stream>>>(qkv, vT, y);
    mfma_gemm_t<128, 64, 64><<<dim3(32, 16), 256, 0, stream>>>(
        y, woT, bo, x, x2, nullptr, nullptr, BT_, C_, C_, C_, 2);

    // MLP branch
    ln_bf16_kernel<<<BT_, 256, 0, stream>>>(x2, ln2_w, ln2_b, h);
    gemm8_t<1><<<dim3(16, 16), 512, 0, stream>>>(
        h, w1T, b1, u, nullptr, BT_, 4 * C_, C_);
    // mlp2: split-K=2 raw partials; reduce adds p1 + bias + res
    mfma_gemm_t<128, 128, 64><<<dim3(32, 8, 2), 256, 0, stream>>>(
        u, w2T, b2, nullptr, out, nullptr, p1, BT_, C_, 2 * C_, 4 * C_, 4);
    splitk_reduce_kernel<<<BT_ * C_ / 1024, 256, 0, stream>>>(out, p1, b2, x2);
}